// Round 9
// baseline (159.627 us; speedup 1.0000x reference)
//
#include <hip/hip_runtime.h>
#include <hip/hip_bf16.h>

// FullAttention fwd, B=4 L=S=2048 H=8 E=D=64, fp32 in/out.
// Round 18: kill the LDS staging entirely. R17 proved the barrier-drain
// theory wrong (counted-vmcnt dbuf = exactly R14's time); audit showed each
// wave's kOff/vOff only touch its OWN s-window -- the LDS round-trip was
// per-wave-private staging (Common-mistake #7: staging L2-resident data).
// New loop: per-wave direct global_load of the 8 K/V fragments per tile
// from the XCD-L2-resident Kc/Vt panels (fragment addresses are 16B
// contiguous: kf = Kc[s0+w*32+pi0(m)][chunk], vf = Vt[dt*16+m][s window]),
// register-double-buffered with explicit named A/B sets, prefetch t+1
// before compute t. No LDS, no barriers, no waitcnt in the loop; waves
// fully independent. LDS only in the one-time epilogue reduce.
// Geometry/math unchanged from R14: 2 waves, qt=4, KVBLK=64, grid 1024,
// f16, cvt_pkrtz pack, ones-MFMA lsum, XCD swizzle.

#define BNUM 4
#define LLEN 2048
#define SLEN 2048
#define HNUM 8
#define EDIM 64

typedef __attribute__((ext_vector_type(8))) short s16x8;     // raw 8x16-bit container
typedef __attribute__((ext_vector_type(8))) _Float16 hf16x8; // f16 MFMA operand
typedef __attribute__((ext_vector_type(2))) __fp16 fp16x2;   // cvt_pkrtz result type
typedef __attribute__((ext_vector_type(4))) float f32x4;

__device__ __forceinline__ short f2h(float f) {
    union { _Float16 h; short s; } u;
    u.h = (_Float16)f;
    return u.s;
}

// pack 8 floats -> 8 f16 (RTZ) in 4 instructions
__device__ __forceinline__ s16x8 pk8(float4 a, float4 b) {
    union { fp16x2 h[4]; s16x8 v; } u;
    u.h[0] = __builtin_amdgcn_cvt_pkrtz(a.x, a.y);
    u.h[1] = __builtin_amdgcn_cvt_pkrtz(a.z, a.w);
    u.h[2] = __builtin_amdgcn_cvt_pkrtz(b.x, b.y);
    u.h[3] = __builtin_amdgcn_cvt_pkrtz(b.z, b.w);
    return u.v;
}

// ---- pre-pass: role 0 = K repack, role 1 = V transpose (f16) ----
__global__ __launch_bounds__(256)
void prep(const float* __restrict__ Kg, const float* __restrict__ Vg,
          short* __restrict__ Kc, short* __restrict__ Vt)
{
    __shared__ short tile[EDIM][80];
    if (blockIdx.y == 0) {
        // K [b][s][h][e] fp32 -> Kc [b][h][s][e] f16
        const int t = blockIdx.x * 256 + threadIdx.x;
        const int e8 = t & 7;
        const int tmp = t >> 3;
        const int h = tmp & 7;
        const int tmp2 = tmp >> 3;
        const int s = tmp2 & (SLEN - 1);
        const int b = tmp2 >> 11;
        const float4* src = (const float4*)(Kg + (((size_t)(b * SLEN + s) * HNUM + h) * EDIM + e8 * 8));
        float4 a = src[0], bb = src[1];
        *(s16x8*)(Kc + ((size_t)((b * HNUM + h) * SLEN + s) * EDIM + e8 * 8)) = pk8(a, bb);
    } else {
        // V [b][s][h][d] fp32 -> Vt [b][h][d][s] f16 (64x64 tile transpose)
        if (blockIdx.x >= 1024) return;
        const int x = blockIdx.x;
        const int s0 = (x & 31) * 64;
        const int bh = x >> 5;
        const int b = bh >> 3, h = bh & 7;
        {
            const int sr = threadIdx.x >> 2, dc = (threadIdx.x & 3) * 16;
            const float4* src = (const float4*)(Vg + (((size_t)(b * SLEN + s0 + sr) * HNUM + h) * EDIM + dc));
            #pragma unroll
            for (int j4 = 0; j4 < 4; ++j4) {
                float4 a = src[j4];
                tile[dc + j4*4 + 0][sr] = f2h(a.x);
                tile[dc + j4*4 + 1][sr] = f2h(a.y);
                tile[dc + j4*4 + 2][sr] = f2h(a.z);
                tile[dc + j4*4 + 3][sr] = f2h(a.w);
            }
        }
        __syncthreads();
        {
            const int dr = threadIdx.x >> 2, sc = (threadIdx.x & 3) * 16;
            short* dst = Vt + ((size_t)((b * HNUM + h) * EDIM + dr) * SLEN + s0 + sc);
            *(s16x8*)dst       = *(const s16x8*)&tile[dr][sc];
            *(s16x8*)(dst + 8) = *(const s16x8*)&tile[dr][sc + 8];
        }
    }
}

// ---- main kernel: barrier-free direct-L2 fragment loop ----
__global__ __launch_bounds__(128, 2)
void fa_fwd(const float* __restrict__ Qg, const short* __restrict__ Kc,
            const short* __restrict__ Vt, float* __restrict__ Og)
{
    __shared__ float sO[64 * 68];   // epilogue only (17408 B)
    __shared__ float sL[2][64];

    const int tid  = threadIdx.x;
    const int wave = tid >> 6;    // s-window index {0,1}
    const int lane = tid & 63;
    const int m    = lane & 15;
    const int quad = lane >> 4;

    // XCD-aware decode: XCD j works logical ids [j*128,(j+1)*128) = 4 (b,h)
    // panels (2 MB f16 K/V) -> L2-resident fragment reads.
    const int lin  = (int)blockIdx.x;
    const int logi = ((lin & 7) << 7) + (lin >> 3);   // nwg=1024, nwg/8=128
    const int qx = logi & 31;
    const int h  = (logi >> 5) & 7;
    const int b  = logi >> 8;
    const int qbase = qx * 64;
    const int bh = b * HNUM + h;

    const short* Kbh = Kc + (size_t)bh * SLEN * EDIM;
    const short* Vbh = Vt + (size_t)bh * EDIM * SLEN;

    // ---- Q fragments (B-op: B[k=e=kb*32+quad*8+j][n=q=qt*16+m]), prescaled ----
    const float csc = 0.18033688011112042f;   // (1/sqrt(64)) * log2(e)
    hf16x8 qfrag[4][2];
    #pragma unroll
    for (int qt = 0; qt < 4; ++qt)
        #pragma unroll
        for (int kb = 0; kb < 2; ++kb) {
            const float* qp = Qg + ((size_t)(b * LLEN + qbase + qt * 16 + m) * HNUM + h) * EDIM
                              + kb * 32 + quad * 8;
            float4 x0 = *(const float4*)qp;
            float4 x1 = *(const float4*)(qp + 4);
            float4 y0 = {x0.x*csc, x0.y*csc, x0.z*csc, x0.w*csc};
            float4 y1 = {x1.x*csc, x1.y*csc, x1.z*csc, x1.w*csc};
            union { s16x8 s; hf16x8 hh; } u;
            u.s = pk8(y0, y1);
            qfrag[qt][kb] = u.hh;
        }

    // ---- per-lane fragment bases (permuted-K trick preserved; no XOR
    // swizzle needed -- that existed only for LDS banks) ----
    const int pi0 = 8 * (m >> 2) + (m & 3);
    const short* kbase = Kbh + (wave * 32 + pi0) * EDIM + quad * 8;
    const short* vbase = Vbh + (size_t)m * SLEN + wave * 32 + quad * 8;

    // all-ones f16 B-operand for the row-sum MFMA
    hf16x8 vones;
    #pragma unroll
    for (int j = 0; j < 8; ++j) vones[j] = (_Float16)1.0f;

    f32x4 oacc[4][4];   // [qt][dt]
    f32x4 lacc[4];      // row-sum accumulators
    #pragma unroll
    for (int i = 0; i < 4; ++i) {
        #pragma unroll
        for (int j = 0; j < 4; ++j) oacc[i][j] = (f32x4){0.f, 0.f, 0.f, 0.f};
        lacc[i] = (f32x4){0.f, 0.f, 0.f, 0.f};
    }

    // fragment register sets A and B (explicit names -- no runtime indexing)
    hf16x8 kA00, kA01, kA10, kA11, vA0, vA1, vA2, vA3;
    hf16x8 kB00, kB01, kB10, kB11, vB0, vB1, vB2, vB3;

#define LOADF(K00, K01, K10, K11, V0, V1, V2, V3, S0)                         \
    do {                                                                      \
        const short* kp = kbase + (size_t)(S0) * EDIM;                        \
        const short* vp = vbase + (S0);                                       \
        K00 = *(const hf16x8*)(kp);                                           \
        K01 = *(const hf16x8*)(kp + 32);                                      \
        K10 = *(const hf16x8*)(kp + 4 * EDIM);                                \
        K11 = *(const hf16x8*)(kp + 4 * EDIM + 32);                           \
        V0  = *(const hf16x8*)(vp);                                           \
        V1  = *(const hf16x8*)(vp + 16 * SLEN);                               \
        V2  = *(const hf16x8*)(vp + 32 * SLEN);                               \
        V3  = *(const hf16x8*)(vp + 48 * SLEN);                               \
    } while (0)

#define COMPUTE(K00, K01, K10, K11, V0, V1, V2, V3)                           \
    do {                                                                      \
        _Pragma("unroll")                                                     \
        for (int qt = 0; qt < 4; ++qt) {                                      \
            f32x4 a0 = {0.f, 0.f, 0.f, 0.f};                                  \
            f32x4 a1 = {0.f, 0.f, 0.f, 0.f};                                  \
            a0 = __builtin_amdgcn_mfma_f32_16x16x32_f16(K00, qfrag[qt][0], a0, 0, 0, 0); \
            a0 = __builtin_amdgcn_mfma_f32_16x16x32_f16(K01, qfrag[qt][1], a0, 0, 0, 0); \
            a1 = __builtin_amdgcn_mfma_f32_16x16x32_f16(K10, qfrag[qt][0], a1, 0, 0, 0); \
            a1 = __builtin_amdgcn_mfma_f32_16x16x32_f16(K11, qfrag[qt][1], a1, 0, 0, 0); \
            float p0 = __builtin_amdgcn_exp2f(a0[0]);                         \
            float p1 = __builtin_amdgcn_exp2f(a0[1]);                         \
            float p2 = __builtin_amdgcn_exp2f(a0[2]);                         \
            float p3 = __builtin_amdgcn_exp2f(a0[3]);                         \
            float p4 = __builtin_amdgcn_exp2f(a1[0]);                         \
            float p5 = __builtin_amdgcn_exp2f(a1[1]);                         \
            float p6 = __builtin_amdgcn_exp2f(a1[2]);                         \
            float p7 = __builtin_amdgcn_exp2f(a1[3]);                         \
            union { fp16x2 h2[4]; hf16x8 v; } pu;                             \
            pu.h2[0] = __builtin_amdgcn_cvt_pkrtz(p0, p1);                    \
            pu.h2[1] = __builtin_amdgcn_cvt_pkrtz(p2, p3);                    \
            pu.h2[2] = __builtin_amdgcn_cvt_pkrtz(p4, p5);                    \
            pu.h2[3] = __builtin_amdgcn_cvt_pkrtz(p6, p7);                    \
            hf16x8 pf = pu.v;                                                 \
            lacc[qt] = __builtin_amdgcn_mfma_f32_16x16x32_f16(pf, vones, lacc[qt], 0, 0, 0); \
            oacc[qt][0] = __builtin_amdgcn_mfma_f32_16x16x32_f16(pf, V0, oacc[qt][0], 0, 0, 0); \
            oacc[qt][1] = __builtin_amdgcn_mfma_f32_16x16x32_f16(pf, V1, oacc[qt][1], 0, 0, 0); \
            oacc[qt][2] = __builtin_amdgcn_mfma_f32_16x16x32_f16(pf, V2, oacc[qt][2], 0, 0, 0); \
            oacc[qt][3] = __builtin_amdgcn_mfma_f32_16x16x32_f16(pf, V3, oacc[qt][3], 0, 0, 0); \
        }                                                                     \
    } while (0)

    // prologue: tile 0 into set A
    LOADF(kA00, kA01, kA10, kA11, vA0, vA1, vA2, vA3, 0);

    // main loop, unrolled x2 with explicit A/B role swap; prefetch t+1
    // before computing t. Clamped prefetch on the tail (re-loads tile 31).
    for (int t = 0; t < 32; t += 2) {
        const int s1 = (t + 1) * 64;                     // t+1 <= 31 always here
        LOADF(kB00, kB01, kB10, kB11, vB0, vB1, vB2, vB3, s1);
        COMPUTE(kA00, kA01, kA10, kA11, vA0, vA1, vA2, vA3);
        const int s2 = (t + 2 < 32) ? (t + 2) * 64 : s1; // clamp tail
        LOADF(kA00, kA01, kA10, kA11, vA0, vA1, vA2, vA3, s2);
        COMPUTE(kB00, kB01, kB10, kB11, vB0, vB1, vB2, vB3);
    }

    // ---- epilogue: lacc holds per-q row-sums (C[row=quad*4+r][col=m], all m equal) ----
    if (m == 0) {
        #pragma unroll
        for (int qt = 0; qt < 4; ++qt)
            #pragma unroll
            for (int r = 0; r < 4; ++r)
                sL[wave][qt * 16 + quad * 4 + r] = lacc[qt][r];
    }
    __syncthreads();

    if (wave == 0) {
        #pragma unroll
        for (int qt = 0; qt < 4; ++qt)
            #pragma unroll
            for (int dt = 0; dt < 4; ++dt)
                #pragma unroll
                for (int r = 0; r < 4; ++r)
                    sO[(qt * 16 + quad * 4 + r) * 68 + dt * 16 + m] = oacc[qt][dt][r];
    }
    __syncthreads();
    if (wave == 1) {
        #pragma unroll
        for (int qt = 0; qt < 4; ++qt)
            #pragma unroll
            for (int dt = 0; dt < 4; ++dt)
                #pragma unroll
                for (int r = 0; r < 4; ++r)
                    sO[(qt * 16 + quad * 4 + r) * 68 + dt * 16 + m] += oacc[qt][dt][r];
    }
    __syncthreads();

    {
        const int q = tid >> 1;            // [0,64)
        const int dcol = (tid & 1) * 32;
        const float l = sL[0][q] + sL[1][q];
        const float inv = 1.0f / l;
        float* orow = Og + ((size_t)(b * LLEN + qbase + q) * HNUM + h) * EDIM + dcol;
        #pragma unroll
        for (int j = 0; j < 8; ++j) {
            float4 v = *(const float4*)(sO + q * 68 + dcol + j * 4);
            v.x *= inv; v.y *= inv; v.z *= inv; v.w *= inv;
            *(float4*)(orow + j * 4) = v;
        }
    }
}

extern "C" void kernel_launch(void* const* d_in, const int* in_sizes, int n_in,
                              void* d_out, int out_size, void* d_ws, size_t ws_size,
                              hipStream_t stream) {
    const float* Q = (const float*)d_in[0];
    const float* K = (const float*)d_in[1];
    const float* V = (const float*)d_in[2];
    float* O = (float*)d_out;

    const size_t NE = (size_t)BNUM * LLEN * HNUM * EDIM;   // 4,194,304
    short* Kc = (short*)d_ws;
    short* Vt = Kc + NE;

    prep<<<dim3(2048, 2), dim3(256), 0, stream>>>(K, V, Kc, Vt);
    fa_fwd<<<dim3(1024), dim3(128), 0, stream>>>(Q, Kc, Vt, O);
}

// Round 10
// 138.633 us; speedup vs baseline: 1.1514x; 1.1514x over previous
//
#include <hip/hip_runtime.h>
#include <hip/hip_bf16.h>

// FullAttention fwd, B=4 L=S=2048 H=8 E=D=64, fp32 in/out.
// Round 19: occupancy x2 at ZERO extra staging. Ledger: R10/R14/R17 all
// ~57-61us despite halved LDS traffic / halved VALU / pipelined DMA; no
// pipe >30% busy => latency-bound on the QK->exp2->pack->PV chain with
// only 2 waves/SIMD. R15 failed because raising occupancy doubled staging;
// this round splits the SAME block's work over 4 waves instead:
// wave=(qh,sw): sw=wave&1 owns s-window sw*32 (R6 formulas' "wave" slot),
// qh=wave>>1 owns q-tiles {2qh,2qh+1}. Staging: waves 0,1 only, R6
// formulas verbatim. Block=256 thr, regs ~100 -> 4 waves/SIMD via
// __launch_bounds__(256,4); grid 1024 = exactly 4 blocks/CU. Total MFMA,
// staging bytes, barrier count per tile all unchanged; wave-level ILP x2.
// f16 + cvt_pkrtz + ones-MFMA lsum + XCD swizzle kept from R14.

#define BNUM 4
#define LLEN 2048
#define SLEN 2048
#define HNUM 8
#define EDIM 64

typedef __attribute__((ext_vector_type(8))) short s16x8;     // raw 8x16-bit container
typedef __attribute__((ext_vector_type(8))) _Float16 hf16x8; // f16 MFMA operand
typedef __attribute__((ext_vector_type(2))) __fp16 fp16x2;   // cvt_pkrtz result type
typedef __attribute__((ext_vector_type(4))) float f32x4;

__device__ __forceinline__ short f2h(float f) {
    union { _Float16 h; short s; } u;
    u.h = (_Float16)f;
    return u.s;
}

// pack 8 floats -> 8 f16 (RTZ) in 4 instructions
__device__ __forceinline__ s16x8 pk8(float4 a, float4 b) {
    union { fp16x2 h[4]; s16x8 v; } u;
    u.h[0] = __builtin_amdgcn_cvt_pkrtz(a.x, a.y);
    u.h[1] = __builtin_amdgcn_cvt_pkrtz(a.z, a.w);
    u.h[2] = __builtin_amdgcn_cvt_pkrtz(b.x, b.y);
    u.h[3] = __builtin_amdgcn_cvt_pkrtz(b.z, b.w);
    return u.v;
}

#if __has_builtin(__builtin_amdgcn_global_load_lds)
#define HAVE_GLL 1
#else
#define HAVE_GLL 0
#endif

__device__ __forceinline__ void stage16(const short* g, short* l) {
#if HAVE_GLL
    __builtin_amdgcn_global_load_lds(
        (const __attribute__((address_space(1))) void*)g,
        (__attribute__((address_space(3))) void*)l, 16, 0, 0);
#else
    *(s16x8*)l = *(const s16x8*)g;
#endif
}

// ---- pre-pass: role 0 = K repack, role 1 = V transpose (f16) ----
__global__ __launch_bounds__(256)
void prep(const float* __restrict__ Kg, const float* __restrict__ Vg,
          short* __restrict__ Kc, short* __restrict__ Vt)
{
    __shared__ short tile[EDIM][80];
    if (blockIdx.y == 0) {
        // K [b][s][h][e] fp32 -> Kc [b][h][s][e] f16
        const int t = blockIdx.x * 256 + threadIdx.x;
        const int e8 = t & 7;
        const int tmp = t >> 3;
        const int h = tmp & 7;
        const int tmp2 = tmp >> 3;
        const int s = tmp2 & (SLEN - 1);
        const int b = tmp2 >> 11;
        const float4* src = (const float4*)(Kg + (((size_t)(b * SLEN + s) * HNUM + h) * EDIM + e8 * 8));
        float4 a = src[0], bb = src[1];
        *(s16x8*)(Kc + ((size_t)((b * HNUM + h) * SLEN + s) * EDIM + e8 * 8)) = pk8(a, bb);
    } else {
        // V [b][s][h][d] fp32 -> Vt [b][h][d][s] f16 (64x64 tile transpose)
        if (blockIdx.x >= 1024) return;
        const int x = blockIdx.x;
        const int s0 = (x & 31) * 64;
        const int bh = x >> 5;
        const int b = bh >> 3, h = bh & 7;
        {
            const int sr = threadIdx.x >> 2, dc = (threadIdx.x & 3) * 16;
            const float4* src = (const float4*)(Vg + (((size_t)(b * SLEN + s0 + sr) * HNUM + h) * EDIM + dc));
            #pragma unroll
            for (int j4 = 0; j4 < 4; ++j4) {
                float4 a = src[j4];
                tile[dc + j4*4 + 0][sr] = f2h(a.x);
                tile[dc + j4*4 + 1][sr] = f2h(a.y);
                tile[dc + j4*4 + 2][sr] = f2h(a.z);
                tile[dc + j4*4 + 3][sr] = f2h(a.w);
            }
        }
        __syncthreads();
        {
            const int dr = threadIdx.x >> 2, sc = (threadIdx.x & 3) * 16;
            short* dst = Vt + ((size_t)((b * HNUM + h) * EDIM + dr) * SLEN + s0 + sc);
            *(s16x8*)dst       = *(const s16x8*)&tile[dr][sc];
            *(s16x8*)(dst + 8) = *(const s16x8*)&tile[dr][sc + 8];
        }
    }
}

// ---- main kernel: R14 block, 4 waves = (qh, sw) ----
// LDS: K region [0:4096) shorts = 64 s-rows x 8 chunks(16B), chunk (r,c) at
// r*8 + (c ^ g(r)), g(r) = ((r>>3)&1)*4 + (r&3); V region [4096:8192) =
// 2 panels (per-sw 32-s window), 64 d-rows x 4 chunks(16B), chunk (d,c) at
// d*4 + (c ^ (d&3)).  [R6 formulas verbatim]
__global__ __launch_bounds__(256, 4)
void fa_fwd(const float* __restrict__ Qg, const short* __restrict__ Kc,
            const short* __restrict__ Vt, float* __restrict__ Og)
{
    __shared__ short sKV[8704];   // 17408 B; staging [0:8192), sO reuse (64x68 f32)
    __shared__ float sL[2][64];

    const int tid  = threadIdx.x;
    const int wave = tid >> 6;    // {0,1,2,3}
    const int sw   = wave & 1;    // s-window index (R6 formulas' "wave" slot)
    const int qh   = wave >> 1;   // q-half: q-tiles {2qh, 2qh+1}
    const int lane = tid & 63;
    const int m    = lane & 15;
    const int quad = lane >> 4;

    // XCD-aware decode: XCD j works logical ids [j*128,(j+1)*128) = 4 (b,h)
    // panels (2 MB f16 K/V) -> L2-resident staging.
    const int lin  = (int)blockIdx.x;
    const int logi = ((lin & 7) << 7) + (lin >> 3);   // nwg=1024, nwg/8=128
    const int qx = logi & 31;
    const int h  = (logi >> 5) & 7;
    const int b  = logi >> 8;
    const int qbase = qx * 64;
    const int bh = b * HNUM + h;

    const short* Kbh = Kc + (size_t)bh * SLEN * EDIM;
    const short* Vbh = Vt + (size_t)bh * EDIM * SLEN;

    // ---- staging bases (R6 formulas verbatim; executed by waves 0,1 only) ----
    const int l3 = lane >> 3;
    const int ksrcE = (wave * 32 + l3) * EDIM + ((lane & 7) ^ (l3 & 3)) * 8;        // p even
    const int ksrcO = (wave * 32 + l3) * EDIM + ((lane & 7) ^ (4 + (l3 & 3))) * 8;  // p odd
    const int vsrcB = (lane >> 2) * SLEN + wave * 32 + ((lane & 3) ^ ((lane >> 2) & 3)) * 8;
    short* kdstB = sKV + (wave * 256 + lane) * 8;
    short* vdstB = sKV + 4096 + (wave * 256 + lane) * 8;

#define STAGE_TILE(s0)                                                        \
    do {                                                                      \
        _Pragma("unroll")                                                     \
        for (int p = 0; p < 4; ++p) {                                         \
            const int ks = ((p & 1) ? ksrcO : ksrcE) + (p >> 1) * 1024 + (p & 1) * 512; \
            stage16(Kbh + (size_t)(s0) * EDIM + ks, kdstB + p * 512);         \
            stage16(Vbh + (s0) + vsrcB + p * 16 * SLEN, vdstB + p * 512);     \
        }                                                                     \
    } while (0)

    // ---- Q fragments for this wave's 2 q-tiles (prescaled) ----
    const float csc = 0.18033688011112042f;   // (1/sqrt(64)) * log2(e)
    hf16x8 qfrag[2][2];
    #pragma unroll
    for (int qtl = 0; qtl < 2; ++qtl)
        #pragma unroll
        for (int kb = 0; kb < 2; ++kb) {
            const int qtg = qh * 2 + qtl;
            const float* qp = Qg + ((size_t)(b * LLEN + qbase + qtg * 16 + m) * HNUM + h) * EDIM
                              + kb * 32 + quad * 8;
            float4 x0 = *(const float4*)qp;
            float4 x1 = *(const float4*)(qp + 4);
            float4 y0 = {x0.x*csc, x0.y*csc, x0.z*csc, x0.w*csc};
            float4 y1 = {x1.x*csc, x1.y*csc, x1.z*csc, x1.w*csc};
            union { s16x8 s; hf16x8 hh; } u;
            u.s = pk8(y0, y1);
            qfrag[qtl][kb] = u.hh;
        }

    // ---- frag read offsets (R6 formulas verbatim, sw in {0,1}) ----
    const int gk  = ((m >> 2) & 1) * 4 + (m & 3);
    const int pi0 = 8 * (m >> 2) + (m & 3);
    const int kOff00 = (sw * 32 + pi0)     * 64 + ((quad)     ^ gk) * 8;
    const int kOff01 = (sw * 32 + pi0)     * 64 + ((4 + quad) ^ gk) * 8;
    const int kOff10 = (sw * 32 + pi0 + 4) * 64 + ((quad)     ^ gk) * 8;
    const int kOff11 = (sw * 32 + pi0 + 4) * 64 + ((4 + quad) ^ gk) * 8;
    const int vOffB  = 4096 + sw * 2048 + m * 32 + ((quad ^ (m & 3)) * 8);

    // all-ones f16 B-operand for the row-sum MFMA
    hf16x8 vones;
    #pragma unroll
    for (int j = 0; j < 8; ++j) vones[j] = (_Float16)1.0f;

    f32x4 oacc[2][4];   // [qtl][dt]
    f32x4 lacc[2];      // row-sum accumulators
    #pragma unroll
    for (int i = 0; i < 2; ++i) {
        #pragma unroll
        for (int j = 0; j < 4; ++j) oacc[i][j] = (f32x4){0.f, 0.f, 0.f, 0.f};
        lacc[i] = (f32x4){0.f, 0.f, 0.f, 0.f};
    }

    if (wave < 2) STAGE_TILE(0);
    __syncthreads();   // tile 0 resident

    for (int s0 = 0; s0 < SLEN; s0 += 64) {
        // ---- LDS -> registers (balanced b128, conflict-free) ----
        hf16x8 kf00 = *(const hf16x8*)(sKV + kOff00);
        hf16x8 kf01 = *(const hf16x8*)(sKV + kOff01);
        hf16x8 kf10 = *(const hf16x8*)(sKV + kOff10);
        hf16x8 kf11 = *(const hf16x8*)(sKV + kOff11);
        hf16x8 vf0 = *(const hf16x8*)(sKV + vOffB);
        hf16x8 vf1 = *(const hf16x8*)(sKV + vOffB + 512);
        hf16x8 vf2 = *(const hf16x8*)(sKV + vOffB + 1024);
        hf16x8 vf3 = *(const hf16x8*)(sKV + vOffB + 1536);

        __syncthreads();   // barrier1: all waves hold the tile in regs

        if (s0 + 64 < SLEN && wave < 2) STAGE_TILE(s0 + 64);   // DMA next; overlaps compute

        // ---- compute: 18 MFMAs per wave per tile ----
        #pragma unroll
        for (int qtl = 0; qtl < 2; ++qtl) {
            f32x4 a0 = {0.f, 0.f, 0.f, 0.f};
            f32x4 a1 = {0.f, 0.f, 0.f, 0.f};
            a0 = __builtin_amdgcn_mfma_f32_16x16x32_f16(kf00, qfrag[qtl][0], a0, 0, 0, 0);
            a0 = __builtin_amdgcn_mfma_f32_16x16x32_f16(kf01, qfrag[qtl][1], a0, 0, 0, 0);
            a1 = __builtin_amdgcn_mfma_f32_16x16x32_f16(kf10, qfrag[qtl][0], a1, 0, 0, 0);
            a1 = __builtin_amdgcn_mfma_f32_16x16x32_f16(kf11, qfrag[qtl][1], a1, 0, 0, 0);
            // a0[r]=S[s_local=8*quad+r][q], a1[r]=S[s_local=8*quad+4+r][q]
            float p0 = __builtin_amdgcn_exp2f(a0[0]);
            float p1 = __builtin_amdgcn_exp2f(a0[1]);
            float p2 = __builtin_amdgcn_exp2f(a0[2]);
            float p3 = __builtin_amdgcn_exp2f(a0[3]);
            float p4 = __builtin_amdgcn_exp2f(a1[0]);
            float p5 = __builtin_amdgcn_exp2f(a1[1]);
            float p6 = __builtin_amdgcn_exp2f(a1[2]);
            float p7 = __builtin_amdgcn_exp2f(a1[3]);
            // A-op: A[q=m][k=s_local=quad*8+j], packed in 4 instrs
            union { fp16x2 h2[4]; hf16x8 v; } pu;
            pu.h2[0] = __builtin_amdgcn_cvt_pkrtz(p0, p1);
            pu.h2[1] = __builtin_amdgcn_cvt_pkrtz(p2, p3);
            pu.h2[2] = __builtin_amdgcn_cvt_pkrtz(p4, p5);
            pu.h2[3] = __builtin_amdgcn_cvt_pkrtz(p6, p7);
            hf16x8 pf = pu.v;
            // row-sum over this wave's 32-s window via ones-MFMA (exact, f32 acc)
            lacc[qtl] = __builtin_amdgcn_mfma_f32_16x16x32_f16(pf, vones, lacc[qtl], 0, 0, 0);
            oacc[qtl][0] = __builtin_amdgcn_mfma_f32_16x16x32_f16(pf, vf0, oacc[qtl][0], 0, 0, 0);
            oacc[qtl][1] = __builtin_amdgcn_mfma_f32_16x16x32_f16(pf, vf1, oacc[qtl][1], 0, 0, 0);
            oacc[qtl][2] = __builtin_amdgcn_mfma_f32_16x16x32_f16(pf, vf2, oacc[qtl][2], 0, 0, 0);
            oacc[qtl][3] = __builtin_amdgcn_mfma_f32_16x16x32_f16(pf, vf3, oacc[qtl][3], 0, 0, 0);
        }

        __syncthreads();   // barrier2: DMA drained after compute; next tile ready
    }

    // ---- epilogue: lacc holds per-q row-sums over window sw ----
    // sL[sw][qtg*16 + quad*4 + r]; (sw,qh) pairs write disjoint slices.
    if (m == 0) {
        #pragma unroll
        for (int qtl = 0; qtl < 2; ++qtl)
            #pragma unroll
            for (int r = 0; r < 4; ++r)
                sL[sw][(qh * 2 + qtl) * 16 + quad * 4 + r] = lacc[qtl][r];
    }
    __syncthreads();

    float* sO = (float*)sKV;   // 64 rows x 68 floats = 17408 B
    if (sw == 0) {             // waves (qh=0,1) write disjoint 32-row halves
        #pragma unroll
        for (int qtl = 0; qtl < 2; ++qtl)
            #pragma unroll
            for (int dt = 0; dt < 4; ++dt)
                #pragma unroll
                for (int r = 0; r < 4; ++r)
                    sO[((qh * 2 + qtl) * 16 + quad * 4 + r) * 68 + dt * 16 + m] = oacc[qtl][dt][r];
    }
    __syncthreads();
    if (sw == 1) {
        #pragma unroll
        for (int qtl = 0; qtl < 2; ++qtl)
            #pragma unroll
            for (int dt = 0; dt < 4; ++dt)
                #pragma unroll
                for (int r = 0; r < 4; ++r)
                    sO[((qh * 2 + qtl) * 16 + quad * 4 + r) * 68 + dt * 16 + m] += oacc[qtl][dt][r];
    }
    __syncthreads();

    {
        const int q = tid >> 2;            // [0,64)
        const int dcol = (tid & 3) * 16;
        const float l = sL[0][q] + sL[1][q];
        const float inv = 1.0f / l;
        float* orow = Og + ((size_t)(b * LLEN + qbase + q) * HNUM + h) * EDIM + dcol;
        #pragma unroll
        for (int j = 0; j < 4; ++j) {
            float4 v = *(const float4*)(sO + q * 68 + dcol + j * 4);
            v.x *= inv; v.y *= inv; v.z *= inv; v.w *= inv;
            *(float4*)(orow + j * 4) = v;
        }
    }
}

extern "C" void kernel_launch(void* const* d_in, const int* in_sizes, int n_in,
                              void* d_out, int out_size, void* d_ws, size_t ws_size,
                              hipStream_t stream) {
    const float* Q = (const float*)d_in[0];
    const float* K = (const float*)d_in[1];
    const float* V = (const float*)d_in[2];
    float* O = (float*)d_out;

    const size_t NE = (size_t)BNUM * LLEN * HNUM * EDIM;   // 4,194,304
    short* Kc = (short*)d_ws;
    short* Vt = Kc + NE;

    prep<<<dim3(2048, 2), dim3(256), 0, stream>>>(K, V, Kc, Vt);
    fa_fwd<<<dim3(1024), dim3(256), 0, stream>>>(Q, Kc, Vt, O);
}

// Round 11
// 137.366 us; speedup vs baseline: 1.1621x; 1.0092x over previous
//
#include <hip/hip_runtime.h>
#include <hip/hip_bf16.h>

// FullAttention fwd, B=4 L=S=2048 H=8 E=D=64, fp32 in/out.
// Round 20: amortize staging further at constant occupancy. Ledger:
// staging-per-FLOP is the only lever that ever moved time (R10 -8%,
// R15 +22%); occupancy alone gave 3% (R19). This round: 8-wave 512-thread
// blocks over 128 q-rows, wave=(qh in 0..3, sw in 0..1); sw feeds the R6
// s-window formulas verbatim, qh owns q-tiles {2qh,2qh+1}; qt=2/wave keeps
// VGPR ~60 -> 4 waves/SIMD (__launch_bounds__(512,4)), grid 512 = exactly
// 2 blocks/CU. Staging bytes + barriers per tile-period per CU HALVE vs
// R19; MFMA/VALU/LDS-read per SIMD unchanged. Same __syncthreads pair
// (proven correct); waves 0,1 stage. Epilogue sO grows to 128x68 f32
// (34.8 KB; 2 blocks/CU -> 71 KB LDS, fine). f16 + cvt_pkrtz + ones-MFMA
// lsum + XCD swizzle kept.

#define BNUM 4
#define LLEN 2048
#define SLEN 2048
#define HNUM 8
#define EDIM 64

typedef __attribute__((ext_vector_type(8))) short s16x8;     // raw 8x16-bit container
typedef __attribute__((ext_vector_type(8))) _Float16 hf16x8; // f16 MFMA operand
typedef __attribute__((ext_vector_type(2))) __fp16 fp16x2;   // cvt_pkrtz result type
typedef __attribute__((ext_vector_type(4))) float f32x4;

__device__ __forceinline__ short f2h(float f) {
    union { _Float16 h; short s; } u;
    u.h = (_Float16)f;
    return u.s;
}

// pack 8 floats -> 8 f16 (RTZ) in 4 instructions
__device__ __forceinline__ s16x8 pk8(float4 a, float4 b) {
    union { fp16x2 h[4]; s16x8 v; } u;
    u.h[0] = __builtin_amdgcn_cvt_pkrtz(a.x, a.y);
    u.h[1] = __builtin_amdgcn_cvt_pkrtz(a.z, a.w);
    u.h[2] = __builtin_amdgcn_cvt_pkrtz(b.x, b.y);
    u.h[3] = __builtin_amdgcn_cvt_pkrtz(b.z, b.w);
    return u.v;
}

#if __has_builtin(__builtin_amdgcn_global_load_lds)
#define HAVE_GLL 1
#else
#define HAVE_GLL 0
#endif

__device__ __forceinline__ void stage16(const short* g, short* l) {
#if HAVE_GLL
    __builtin_amdgcn_global_load_lds(
        (const __attribute__((address_space(1))) void*)g,
        (__attribute__((address_space(3))) void*)l, 16, 0, 0);
#else
    *(s16x8*)l = *(const s16x8*)g;
#endif
}

// ---- pre-pass: role 0 = K repack, role 1 = V transpose (f16) ----
__global__ __launch_bounds__(256)
void prep(const float* __restrict__ Kg, const float* __restrict__ Vg,
          short* __restrict__ Kc, short* __restrict__ Vt)
{
    __shared__ short tile[EDIM][80];
    if (blockIdx.y == 0) {
        // K [b][s][h][e] fp32 -> Kc [b][h][s][e] f16
        const int t = blockIdx.x * 256 + threadIdx.x;
        const int e8 = t & 7;
        const int tmp = t >> 3;
        const int h = tmp & 7;
        const int tmp2 = tmp >> 3;
        const int s = tmp2 & (SLEN - 1);
        const int b = tmp2 >> 11;
        const float4* src = (const float4*)(Kg + (((size_t)(b * SLEN + s) * HNUM + h) * EDIM + e8 * 8));
        float4 a = src[0], bb = src[1];
        *(s16x8*)(Kc + ((size_t)((b * HNUM + h) * SLEN + s) * EDIM + e8 * 8)) = pk8(a, bb);
    } else {
        // V [b][s][h][d] fp32 -> Vt [b][h][d][s] f16 (64x64 tile transpose)
        if (blockIdx.x >= 1024) return;
        const int x = blockIdx.x;
        const int s0 = (x & 31) * 64;
        const int bh = x >> 5;
        const int b = bh >> 3, h = bh & 7;
        {
            const int sr = threadIdx.x >> 2, dc = (threadIdx.x & 3) * 16;
            const float4* src = (const float4*)(Vg + (((size_t)(b * SLEN + s0 + sr) * HNUM + h) * EDIM + dc));
            #pragma unroll
            for (int j4 = 0; j4 < 4; ++j4) {
                float4 a = src[j4];
                tile[dc + j4*4 + 0][sr] = f2h(a.x);
                tile[dc + j4*4 + 1][sr] = f2h(a.y);
                tile[dc + j4*4 + 2][sr] = f2h(a.z);
                tile[dc + j4*4 + 3][sr] = f2h(a.w);
            }
        }
        __syncthreads();
        {
            const int dr = threadIdx.x >> 2, sc = (threadIdx.x & 3) * 16;
            short* dst = Vt + ((size_t)((b * HNUM + h) * EDIM + dr) * SLEN + s0 + sc);
            *(s16x8*)dst       = *(const s16x8*)&tile[dr][sc];
            *(s16x8*)(dst + 8) = *(const s16x8*)&tile[dr][sc + 8];
        }
    }
}

// ---- main kernel: 8 waves = (qh 0..3, sw 0..1), 128 q-rows, KVBLK=64 ----
// LDS staging region (8192 shorts, aliased onto sO): K [0:4096) = 64 s-rows
// x 8 chunks(16B), chunk (r,c) at r*8 + (c ^ g(r)), g(r)=((r>>3)&1)*4+(r&3);
// V [4096:8192) = 2 panels (per-sw 32-s window), 64 d-rows x 4 chunks(16B),
// chunk (d,c) at d*4 + (c ^ (d&3)).  [R6 formulas verbatim]
__global__ __launch_bounds__(512, 4)
void fa_fwd(const float* __restrict__ Qg, const short* __restrict__ Kc,
            const short* __restrict__ Vt, float* __restrict__ Og)
{
    __shared__ float sOf[128 * 68];   // 34816 B; staging aliases first 16 KB
    __shared__ float sL[2][128];
    short* sKV = (short*)sOf;

    const int tid  = threadIdx.x;
    const int wave = tid >> 6;    // {0..7}
    const int sw   = wave & 1;    // s-window index (R6 formulas' "wave" slot)
    const int qh   = wave >> 1;   // q-quarter: q-tiles {2qh, 2qh+1}
    const int lane = tid & 63;
    const int m    = lane & 15;
    const int quad = lane >> 4;

    // XCD-aware decode: XCD j works logical ids [j*64,(j+1)*64) = 4 (b,h)
    // panels (2 MB f16 K/V) -> L2-resident staging.
    const int lin  = (int)blockIdx.x;
    const int logi = ((lin & 7) << 6) + (lin >> 3);   // nwg=512, nwg/8=64
    const int qx = logi & 15;
    const int h  = (logi >> 4) & 7;
    const int b  = logi >> 7;
    const int qbase = qx * 128;
    const int bh = b * HNUM + h;

    const short* Kbh = Kc + (size_t)bh * SLEN * EDIM;
    const short* Vbh = Vt + (size_t)bh * EDIM * SLEN;

    // ---- staging bases (R6 formulas verbatim; executed by waves 0,1 only) ----
    const int l3 = lane >> 3;
    const int ksrcE = (wave * 32 + l3) * EDIM + ((lane & 7) ^ (l3 & 3)) * 8;        // p even
    const int ksrcO = (wave * 32 + l3) * EDIM + ((lane & 7) ^ (4 + (l3 & 3))) * 8;  // p odd
    const int vsrcB = (lane >> 2) * SLEN + wave * 32 + ((lane & 3) ^ ((lane >> 2) & 3)) * 8;
    short* kdstB = sKV + (wave * 256 + lane) * 8;
    short* vdstB = sKV + 4096 + (wave * 256 + lane) * 8;

#define STAGE_TILE(s0)                                                        \
    do {                                                                      \
        _Pragma("unroll")                                                     \
        for (int p = 0; p < 4; ++p) {                                         \
            const int ks = ((p & 1) ? ksrcO : ksrcE) + (p >> 1) * 1024 + (p & 1) * 512; \
            stage16(Kbh + (size_t)(s0) * EDIM + ks, kdstB + p * 512);         \
            stage16(Vbh + (s0) + vsrcB + p * 16 * SLEN, vdstB + p * 512);     \
        }                                                                     \
    } while (0)

    // ---- Q fragments for this wave's 2 q-tiles (prescaled) ----
    const float csc = 0.18033688011112042f;   // (1/sqrt(64)) * log2(e)
    hf16x8 qfrag[2][2];
    #pragma unroll
    for (int qtl = 0; qtl < 2; ++qtl)
        #pragma unroll
        for (int kb = 0; kb < 2; ++kb) {
            const int qtg = qh * 2 + qtl;
            const float* qp = Qg + ((size_t)(b * LLEN + qbase + qtg * 16 + m) * HNUM + h) * EDIM
                              + kb * 32 + quad * 8;
            float4 x0 = *(const float4*)qp;
            float4 x1 = *(const float4*)(qp + 4);
            float4 y0 = {x0.x*csc, x0.y*csc, x0.z*csc, x0.w*csc};
            float4 y1 = {x1.x*csc, x1.y*csc, x1.z*csc, x1.w*csc};
            union { s16x8 s; hf16x8 hh; } u;
            u.s = pk8(y0, y1);
            qfrag[qtl][kb] = u.hh;
        }

    // ---- frag read offsets (R6 formulas verbatim, sw in {0,1}) ----
    const int gk  = ((m >> 2) & 1) * 4 + (m & 3);
    const int pi0 = 8 * (m >> 2) + (m & 3);
    const int kOff00 = (sw * 32 + pi0)     * 64 + ((quad)     ^ gk) * 8;
    const int kOff01 = (sw * 32 + pi0)     * 64 + ((4 + quad) ^ gk) * 8;
    const int kOff10 = (sw * 32 + pi0 + 4) * 64 + ((quad)     ^ gk) * 8;
    const int kOff11 = (sw * 32 + pi0 + 4) * 64 + ((4 + quad) ^ gk) * 8;
    const int vOffB  = 4096 + sw * 2048 + m * 32 + ((quad ^ (m & 3)) * 8);

    // all-ones f16 B-operand for the row-sum MFMA
    hf16x8 vones;
    #pragma unroll
    for (int j = 0; j < 8; ++j) vones[j] = (_Float16)1.0f;

    f32x4 oacc[2][4];   // [qtl][dt]
    f32x4 lacc[2];      // row-sum accumulators
    #pragma unroll
    for (int i = 0; i < 2; ++i) {
        #pragma unroll
        for (int j = 0; j < 4; ++j) oacc[i][j] = (f32x4){0.f, 0.f, 0.f, 0.f};
        lacc[i] = (f32x4){0.f, 0.f, 0.f, 0.f};
    }

    if (wave < 2) STAGE_TILE(0);
    __syncthreads();   // tile 0 resident

    for (int s0 = 0; s0 < SLEN; s0 += 64) {
        // ---- LDS -> registers (balanced b128, conflict-free) ----
        hf16x8 kf00 = *(const hf16x8*)(sKV + kOff00);
        hf16x8 kf01 = *(const hf16x8*)(sKV + kOff01);
        hf16x8 kf10 = *(const hf16x8*)(sKV + kOff10);
        hf16x8 kf11 = *(const hf16x8*)(sKV + kOff11);
        hf16x8 vf0 = *(const hf16x8*)(sKV + vOffB);
        hf16x8 vf1 = *(const hf16x8*)(sKV + vOffB + 512);
        hf16x8 vf2 = *(const hf16x8*)(sKV + vOffB + 1024);
        hf16x8 vf3 = *(const hf16x8*)(sKV + vOffB + 1536);

        __syncthreads();   // barrier1: all waves hold the tile in regs

        if (s0 + 64 < SLEN && wave < 2) STAGE_TILE(s0 + 64);   // DMA next; overlaps compute

        // ---- compute: 18 MFMAs per wave per tile ----
        #pragma unroll
        for (int qtl = 0; qtl < 2; ++qtl) {
            f32x4 a0 = {0.f, 0.f, 0.f, 0.f};
            f32x4 a1 = {0.f, 0.f, 0.f, 0.f};
            a0 = __builtin_amdgcn_mfma_f32_16x16x32_f16(kf00, qfrag[qtl][0], a0, 0, 0, 0);
            a0 = __builtin_amdgcn_mfma_f32_16x16x32_f16(kf01, qfrag[qtl][1], a0, 0, 0, 0);
            a1 = __builtin_amdgcn_mfma_f32_16x16x32_f16(kf10, qfrag[qtl][0], a1, 0, 0, 0);
            a1 = __builtin_amdgcn_mfma_f32_16x16x32_f16(kf11, qfrag[qtl][1], a1, 0, 0, 0);
            // a0[r]=S[s_local=8*quad+r][q], a1[r]=S[s_local=8*quad+4+r][q]
            float p0 = __builtin_amdgcn_exp2f(a0[0]);
            float p1 = __builtin_amdgcn_exp2f(a0[1]);
            float p2 = __builtin_amdgcn_exp2f(a0[2]);
            float p3 = __builtin_amdgcn_exp2f(a0[3]);
            float p4 = __builtin_amdgcn_exp2f(a1[0]);
            float p5 = __builtin_amdgcn_exp2f(a1[1]);
            float p6 = __builtin_amdgcn_exp2f(a1[2]);
            float p7 = __builtin_amdgcn_exp2f(a1[3]);
            // A-op: A[q=m][k=s_local=quad*8+j], packed in 4 instrs
            union { fp16x2 h2[4]; hf16x8 v; } pu;
            pu.h2[0] = __builtin_amdgcn_cvt_pkrtz(p0, p1);
            pu.h2[1] = __builtin_amdgcn_cvt_pkrtz(p2, p3);
            pu.h2[2] = __builtin_amdgcn_cvt_pkrtz(p4, p5);
            pu.h2[3] = __builtin_amdgcn_cvt_pkrtz(p6, p7);
            hf16x8 pf = pu.v;
            // row-sum over this wave's 32-s window via ones-MFMA (exact, f32 acc)
            lacc[qtl] = __builtin_amdgcn_mfma_f32_16x16x32_f16(pf, vones, lacc[qtl], 0, 0, 0);
            oacc[qtl][0] = __builtin_amdgcn_mfma_f32_16x16x32_f16(pf, vf0, oacc[qtl][0], 0, 0, 0);
            oacc[qtl][1] = __builtin_amdgcn_mfma_f32_16x16x32_f16(pf, vf1, oacc[qtl][1], 0, 0, 0);
            oacc[qtl][2] = __builtin_amdgcn_mfma_f32_16x16x32_f16(pf, vf2, oacc[qtl][2], 0, 0, 0);
            oacc[qtl][3] = __builtin_amdgcn_mfma_f32_16x16x32_f16(pf, vf3, oacc[qtl][3], 0, 0, 0);
        }

        __syncthreads();   // barrier2: DMA drained after compute; next tile ready
    }

    // ---- epilogue: lacc holds per-q row-sums over window sw ----
    // (sw, qh) pairs write disjoint sL slices.
    if (m == 0) {
        #pragma unroll
        for (int qtl = 0; qtl < 2; ++qtl)
            #pragma unroll
            for (int r = 0; r < 4; ++r)
                sL[sw][(qh * 2 + qtl) * 16 + quad * 4 + r] = lacc[qtl][r];
    }
    __syncthreads();

    // sO: 128 rows x 68 floats (aliases staging region; loop is done)
    if (sw == 0) {             // qh=0..3 write disjoint 32-row quarters
        #pragma unroll
        for (int qtl = 0; qtl < 2; ++qtl)
            #pragma unroll
            for (int dt = 0; dt < 4; ++dt)
                #pragma unroll
                for (int r = 0; r < 4; ++r)
                    sOf[((qh * 2 + qtl) * 16 + quad * 4 + r) * 68 + dt * 16 + m] = oacc[qtl][dt][r];
    }
    __syncthreads();
    if (sw == 1) {
        #pragma unroll
        for (int qtl = 0; qtl < 2; ++qtl)
            #pragma unroll
            for (int dt = 0; dt < 4; ++dt)
                #pragma unroll
                for (int r = 0; r < 4; ++r)
                    sOf[((qh * 2 + qtl) * 16 + quad * 4 + r) * 68 + dt * 16 + m] += oacc[qtl][dt][r];
    }
    __syncthreads();

    {
        const int q = tid >> 2;            // [0,128)
        const int dcol = (tid & 3) * 16;
        const float l = sL[0][q] + sL[1][q];
        const float inv = 1.0f / l;
        float* orow = Og + ((size_t)(b * LLEN + qbase + q) * HNUM + h) * EDIM + dcol;
        #pragma unroll
        for (int j = 0; j < 4; ++j) {
            float4 v = *(const float4*)(sOf + q * 68 + dcol + j * 4);
            v.x *= inv; v.y *= inv; v.z *= inv; v.w *= inv;
            *(float4*)(orow + j * 4) = v;
        }
    }
}

extern "C" void kernel_launch(void* const* d_in, const int* in_sizes, int n_in,
                              void* d_out, int out_size, void* d_ws, size_t ws_size,
                              hipStream_t stream) {
    const float* Q = (const float*)d_in[0];
    const float* K = (const float*)d_in[1];
    const float* V = (const float*)d_in[2];
    float* O = (float*)d_out;

    const size_t NE = (size_t)BNUM * LLEN * HNUM * EDIM;   // 4,194,304
    short* Kc = (short*)d_ws;
    short* Vt = Kc + NE;

    prep<<<dim3(2048, 2), dim3(256), 0, stream>>>(K, V, Kc, Vt);
    fa_fwd<<<dim3(512), dim3(512), 0, stream>>>(Q, Kc, Vt, O);
}